// Round 5
// baseline (1128.933 us; speedup 1.0000x reference)
//
#include <hip/hip_runtime.h>
#include <hip/hip_bf16.h>

// -------------------------------------------------------------------------
// SAGEConv encoder, 2 layers.
// Identity: mean_agg(x) @ Wl^T == mean_agg(x @ Wl^T)  (linearity).
// Identity: normalize(v) @ W == (v @ W) * (1/||v||)   (norm into epilogue).
// Per layer:
//   1) MFMA GEMM: yl = A@Wl^T -> channel-sliced ytab[8][N][16] (bf16),
//      yr = A@Wr^T (bf16), optional per-row rinv scaling (layer 2).
//   2) slice_gather: XCD-affine gather-mean over ytab slice (L2-resident)
//      + yr + bias -> pre-norm v (bf16)
//   3) norm kernel: rinv (layer 1) or final normalize -> f32 out (layer 2)
// CSR built once via 2-level binning; deg-scan fused into bucket kernel.
// -------------------------------------------------------------------------

typedef __attribute__((ext_vector_type(8))) short bf16x8;
typedef __attribute__((ext_vector_type(4))) float f32x4;

__device__ __forceinline__ ushort f2bf(float f) {
    uint u = __float_as_uint(f);
    uint r = (u + 0x7FFFu + ((u >> 16) & 1u)) >> 16;   // RNE
    return (ushort)r;
}
__device__ __forceinline__ float bflo(uint u) { return __uint_as_float(u << 16); }
__device__ __forceinline__ float bfhi(uint u) { return __uint_as_float(u & 0xFFFF0000u); }

// ---- edge_index dtype detection (int32 vs int64) -------------------------
__global__ void detect_kernel(const int* __restrict__ ei, int* __restrict__ flag) {
    if (threadIdx.x == 0 && blockIdx.x == 0) {
        int z = 1;
        for (int j = 0; j < 64; ++j)
            if (ei[2 * j + 1] != 0) { z = 0; break; }
        *flag = z;  // 1 -> int64, 0 -> int32
    }
}

__device__ __forceinline__ int load_idx(const void* ei, int is64, size_t i) {
    return is64 ? (int)((const long long*)ei)[i] : ((const int*)ei)[i];
}

// ---- coarse bucket histogram (bucket = dst>>9, 256 buckets) --------------
__global__ __launch_bounds__(256) void bucket_count_kernel(
    const void* __restrict__ ei, const int* __restrict__ flagp,
    int* __restrict__ bcount, int E) {
    __shared__ int h[256];
    h[threadIdx.x] = 0;
    __syncthreads();
    const int is64 = *flagp;
    for (int i = blockIdx.x * 256 + threadIdx.x; i < E; i += gridDim.x * 256) {
        const int d = load_idx(ei, is64, (size_t)E + i);
        atomicAdd(&h[d >> 9], 1);
    }
    __syncthreads();
    atomicAdd(&bcount[threadIdx.x], h[threadIdx.x]);
}

// ---- 256-entry exclusive scan of bucket counts; also writes rs[N]=E ------
__global__ void bucket_scan_kernel(const int* __restrict__ bcount,
                                   int* __restrict__ bbase, int* __restrict__ bcursor,
                                   int* __restrict__ rs, int N) {
    __shared__ int wt[4];
    const int tid = threadIdx.x, lane = tid & 63, wid = tid >> 6;
    const int v = bcount[tid];
    int incl = v;
    for (int d = 1; d < 64; d <<= 1) {
        int up = __shfl_up(incl, d, 64);
        if (lane >= d) incl += up;
    }
    if (lane == 63) wt[wid] = incl;
    __syncthreads();
    int woff = 0;
    for (int w = 0; w < wid; ++w) woff += wt[w];
    const int excl = woff + incl - v;
    bbase[tid] = excl;
    bcursor[tid] = excl;
    if (tid == 255) {
        bbase[256] = woff + incl;   // == E
        rs[N] = woff + incl;
    }
}

// ---- scatter packed (dstlocal<<17)|src into bucket regions ---------------
__global__ __launch_bounds__(256) void bin_scatter_kernel(
    const void* __restrict__ ei, const int* __restrict__ flagp,
    int* __restrict__ bcursor, uint* __restrict__ pairbuf, int E, int ntiles) {
    __shared__ int cnt[256], pos[256];
    const int tid = threadIdx.x;
    const int is64 = *flagp;
    for (int tile = blockIdx.x; tile < ntiles; tile += gridDim.x) {
        const int base = tile * 2048;
        cnt[tid] = 0;
        __syncthreads();
        int eb[8];
        uint ep[8];
#pragma unroll
        for (int j = 0; j < 8; ++j) {
            const int i = base + tid * 8 + j;
            if (i < E) {
                const int s = load_idx(ei, is64, (size_t)i);
                const int d = load_idx(ei, is64, (size_t)E + i);
                eb[j] = d >> 9;
                ep[j] = ((uint)(d & 511) << 17) | (uint)s;
                atomicAdd(&cnt[eb[j]], 1);
            } else {
                eb[j] = -1;
            }
        }
        __syncthreads();
        pos[tid] = atomicAdd(&bcursor[tid], cnt[tid]);   // reserve range
        __syncthreads();
#pragma unroll
        for (int j = 0; j < 8; ++j) {
            if (eb[j] >= 0) {
                const int p = atomicAdd(&pos[eb[j]], 1);
                pairbuf[p] = ep[j];
            }
        }
    }
}

// ---- per-bucket degree count + fused exclusive scan -> rs, invd ----------
__global__ __launch_bounds__(256) void bucket_degscan_kernel(
    const uint* __restrict__ pairbuf, const int* __restrict__ bbase,
    int* __restrict__ rs, float* __restrict__ invd, int N) {
    __shared__ int dg[512];
    __shared__ int wt[4];
    const int tid = threadIdx.x, lane = tid & 63, wid = tid >> 6, wg = blockIdx.x;
    dg[tid] = 0;
    dg[tid + 256] = 0;
    __syncthreads();
    const int s = bbase[wg], e = bbase[wg + 1];
    for (int i = s + tid; i < e; i += 256)
        atomicAdd(&dg[pairbuf[i] >> 17], 1);
    __syncthreads();
    const int d0 = dg[2 * tid], d1 = dg[2 * tid + 1];
    const int v = d0 + d1;
    int incl = v;
    for (int d = 1; d < 64; d <<= 1) {
        int up = __shfl_up(incl, d, 64);
        if (lane >= d) incl += up;
    }
    if (lane == 63) wt[wid] = incl;
    __syncthreads();
    int woff = 0;
    for (int w = 0; w < wid; ++w) woff += wt[w];
    const int excl = woff + incl - v + bbase[wg];
    const int node = wg * 512 + 2 * tid;
    if (node < N) {
        rs[node] = excl;
        invd[node] = 1.0f / (float)(d0 > 1 ? d0 : 1);
    }
    if (node + 1 < N) {
        rs[node + 1] = excl + d0;
        invd[node + 1] = 1.0f / (float)(d1 > 1 ? d1 : 1);
    }
}

// ---- per-bucket CSR fill with LDS cursors --------------------------------
__global__ __launch_bounds__(256) void bucket_fill_kernel(
    const uint* __restrict__ pairbuf, const int* __restrict__ bbase,
    const int* __restrict__ rs, int* __restrict__ csr, int N) {
    __shared__ int cur[512];
    const int tid = threadIdx.x, wg = blockIdx.x;
#pragma unroll
    for (int t = tid; t < 512; t += 256) {
        const int node = wg * 512 + t;
        cur[t] = (node < N) ? rs[node] : 0;
    }
    __syncthreads();
    const int s = bbase[wg], e = bbase[wg + 1];
    for (int i = s + tid; i < e; i += 256) {
        const uint p = pairbuf[i];
        const int pos = atomicAdd(&cur[p >> 17], 1);
        csr[pos] = (int)(p & 0x1FFFFu);
    }
}

// ---- pack W into MFMA B-fragment layout ----------------------------------
__global__ void pack_w_kernel(const float* __restrict__ Wl1, const float* __restrict__ Wr1,
                              const float* __restrict__ Wl2, const float* __restrict__ Wr2,
                              ushort* __restrict__ Wp) {
    const int gtid = blockIdx.x * 256 + threadIdx.x;   // [0, 8192)
    if (gtid >= 8192) return;
    const int layer = gtid >> 12;
    const int c16   = gtid & 4095;
    const int s     = c16 >> 10;
    const int t     = (c16 >> 6) & 15;
    const int lane  = c16 & 63;
    const int c     = t * 16 + (lane & 15);
    const int kbase = s * 32 + (lane >> 4) * 8;
    const float* Wl = layer ? Wl2 : Wl1;
    const float* Wr = layer ? Wr2 : Wr1;
    const float* src = (c < 128) ? (Wl + c * 128 + kbase) : (Wr + (c - 128) * 128 + kbase);
    ushort* dst = Wp + (size_t)layer * 32768 + (size_t)c16 * 8;
#pragma unroll
    for (int j = 0; j < 8; ++j) dst[j] = f2bf(src[j]);
}

// ---- MFMA GEMM -----------------------------------------------------------
// A [n][128] (f32 if AF32 else bf16) @ W[256][128]^T.
// Outputs: cols 0..127 -> ytab[8][n][16] bf16 (channel-sliced yl),
//          cols 128..255 -> yr[n][128] bf16.
// SCALED: multiply each output row by rinv[row] (fused normalize of A).
template <int AF32, int SCALED>
__global__ __launch_bounds__(256) void sage_mfma_gemm(
    const void* __restrict__ Av, const ushort* __restrict__ Wp,
    const float* __restrict__ rinv,
    ushort* __restrict__ ytab, ushort* __restrict__ yr, int n, int mtiles) {
    __shared__ ushort Wlds[32768];
    for (int i = threadIdx.x; i < 4096; i += 256)
        *(bf16x8*)&Wlds[(size_t)i * 8] = *(const bf16x8*)&Wp[(size_t)i * 8];
    __syncthreads();

    const int wid = threadIdx.x >> 6, lane = threadIdx.x & 63;
    const int koff = (lane >> 4) * 8;
    const int rsub = lane & 15;

    int mt = blockIdx.x;
    if (mt >= mtiles) return;

    auto load_frags = [&](int arow, bf16x8* a) {
        if (AF32) {
            const float* ap = (const float*)Av + ((size_t)arow << 7) + koff;
#pragma unroll
            for (int s = 0; s < 4; ++s) {
                const float4 f0 = *(const float4*)(ap + s * 32);
                const float4 f1 = *(const float4*)(ap + s * 32 + 4);
                bf16x8 r;
                r[0] = (short)f2bf(f0.x); r[1] = (short)f2bf(f0.y);
                r[2] = (short)f2bf(f0.z); r[3] = (short)f2bf(f0.w);
                r[4] = (short)f2bf(f1.x); r[5] = (short)f2bf(f1.y);
                r[6] = (short)f2bf(f1.z); r[7] = (short)f2bf(f1.w);
                a[s] = r;
            }
        } else {
            const ushort* ap = (const ushort*)Av + ((size_t)arow << 7) + koff;
#pragma unroll
            for (int s = 0; s < 4; ++s) a[s] = *(const bf16x8*)(ap + s * 32);
        }
    };

    bf16x8 a_cur[4], a_nxt[4];
    {
        int arow = mt * 64 + wid * 16 + rsub;
        if (arow >= n) arow = 0;
        load_frags(arow, a_cur);
    }

    while (true) {
        const int mtn = mt + gridDim.x;
        if (mtn < mtiles) {
            int arow = mtn * 64 + wid * 16 + rsub;
            if (arow >= n) arow = 0;
            load_frags(arow, a_nxt);
        }

        f32x4 acc[16];
        const f32x4 zero = {0.f, 0.f, 0.f, 0.f};
#pragma unroll
        for (int t = 0; t < 16; ++t) acc[t] = zero;

#pragma unroll
        for (int s = 0; s < 4; ++s) {
            const bf16x8 as = a_cur[s];
#pragma unroll
            for (int t = 0; t < 16; ++t) {
                const bf16x8 b = *(const bf16x8*)&Wlds[(size_t)((s * 16 + t) * 64 + lane) * 8];
                acc[t] = __builtin_amdgcn_mfma_f32_16x16x32_bf16(as, b, acc[t], 0, 0, 0);
            }
        }

        // epilogue: C/D layout col=lane&15, row=(lane>>4)*4+reg
        const int rowb = mt * 64 + wid * 16 + (lane >> 4) * 4;
        float rn[4];
#pragma unroll
        for (int r = 0; r < 4; ++r)
            rn[r] = SCALED ? ((rowb + r < n) ? rinv[rowb + r] : 0.f) : 1.0f;

#pragma unroll
        for (int t = 0; t < 16; ++t) {
#pragma unroll
            for (int r = 0; r < 4; ++r) {
                const int row = rowb + r;
                if (row < n) {
                    const float val = SCALED ? acc[t][r] * rn[r] : acc[t][r];
                    if (t < 8)
                        ytab[(size_t)t * n * 16 + (size_t)row * 16 + rsub] = f2bf(val);
                    else
                        yr[((size_t)row << 7) + (t - 8) * 16 + rsub] = f2bf(val);
                }
            }
        }

        if (mtn >= mtiles) break;
        mt = mtn;
#pragma unroll
        for (int s = 0; s < 4; ++s) a_cur[s] = a_nxt[s];
    }
}

// ---- XCD-affine slice gather-mean + yr + bias -> pre-norm v (bf16) -------
// Grid = 1024 blocks: slice = bid%8 (rides the round-robin block->XCD map),
// so each XCD gathers only its 3.2MB slice table -> L2-resident.
// 8 groups of 8 lanes per wave: 8 edges per wave-load, unroll 2.
__global__ __launch_bounds__(256) void slice_gather_kernel(
    const ushort* __restrict__ ytab, const ushort* __restrict__ yr,
    const float* __restrict__ bias, const int* __restrict__ csr,
    const int* __restrict__ rs, const float* __restrict__ invd,
    ushort* __restrict__ v, int N) {
    const int slice = blockIdx.x & 7;
    const int sb    = blockIdx.x >> 3;          // [0,128)
    const int wid = threadIdx.x >> 6, lane = threadIdx.x & 63;
    const int g = lane >> 3, t = lane & 7;
    const ushort* tab = ytab + (size_t)slice * N * 16;
    const float2 b2 = *(const float2*)(bias + slice * 16 + 2 * t);

    for (int node = sb * 4 + wid; node < N; node += 512) {
        const int s = __builtin_nontemporal_load(&rs[node]);
        const int e = __builtin_nontemporal_load(&rs[node + 1]);
        float ax = 0.f, ay = 0.f;
        int q = s + g;
        for (; q + 8 < e; q += 16) {
            const int s0 = __builtin_nontemporal_load(&csr[q]);
            const int s1 = __builtin_nontemporal_load(&csr[q + 8]);
            const uint u0 = *(const uint*)(tab + ((size_t)s0 << 4) + 2 * t);
            const uint u1 = *(const uint*)(tab + ((size_t)s1 << 4) + 2 * t);
            ax += bflo(u0) + bflo(u1);
            ay += bfhi(u0) + bfhi(u1);
        }
        if (q < e) {
            const int s0 = __builtin_nontemporal_load(&csr[q]);
            const uint u0 = *(const uint*)(tab + ((size_t)s0 << 4) + 2 * t);
            ax += bflo(u0);
            ay += bfhi(u0);
        }
        ax += __shfl_xor(ax, 8, 64);  ay += __shfl_xor(ay, 8, 64);
        ax += __shfl_xor(ax, 16, 64); ay += __shfl_xor(ay, 16, 64);
        ax += __shfl_xor(ax, 32, 64); ay += __shfl_xor(ay, 32, 64);
        if (g == 0) {
            const float iv = invd[node];
            const uint uyr = *(const uint*)(yr + ((size_t)node << 7) + slice * 16 + 2 * t);
            const float vx = fmaf(ax, iv, bflo(uyr) + b2.x);
            const float vy = fmaf(ay, iv, bfhi(uyr) + b2.y);
            const uint o = (uint)f2bf(vx) | ((uint)f2bf(vy) << 16);
            __builtin_nontemporal_store(o, (uint*)(v + (size_t)node * 128 + slice * 16 + 2 * t));
        }
    }
}

// ---- row L2-norm: FINAL=0 -> rinv[node]; FINAL=1 -> f32 normalized out ---
template <int FINAL>
__global__ __launch_bounds__(256) void norm_kernel(
    const ushort* __restrict__ v, float* __restrict__ rinv,
    float* __restrict__ out, int N) {
    const int wid = threadIdx.x >> 6, lane = threadIdx.x & 63;
    const int node = blockIdx.x * 4 + wid;
    if (node >= N) return;
    const uint u = *(const uint*)(v + ((size_t)node << 7) + 2 * lane);
    const float vx = bflo(u), vy = bfhi(u);
    float ss = fmaf(vx, vx, vy * vy);
    ss += __shfl_xor(ss, 1, 64);
    ss += __shfl_xor(ss, 2, 64);
    ss += __shfl_xor(ss, 4, 64);
    ss += __shfl_xor(ss, 8, 64);
    ss += __shfl_xor(ss, 16, 64);
    ss += __shfl_xor(ss, 32, 64);
    const float sc = 1.0f / fmaxf(sqrtf(ss), 1e-12f);
    if (FINAL) {
        ((float2*)out)[((size_t)node << 6) + lane] = make_float2(vx * sc, vy * sc);
    } else if (lane == 0) {
        rinv[node] = sc;
    }
}

// -------------------------------------------------------------------------
extern "C" void kernel_launch(void* const* d_in, const int* in_sizes, int n_in,
                              void* d_out, int out_size, void* d_ws, size_t ws_size,
                              hipStream_t stream) {
    const float* x   = (const float*)d_in[0];
    const void*  ei  = d_in[1];
    const float* Wl1 = (const float*)d_in[2];
    const float* bl1 = (const float*)d_in[3];
    const float* Wr1 = (const float*)d_in[4];
    const float* Wl2 = (const float*)d_in[5];
    const float* bl2 = (const float*)d_in[6];
    const float* Wr2 = (const float*)d_in[7];
    float* out = (float*)d_out;

    const int N = in_sizes[0] / 128;
    const int E = in_sizes[1] / 2;

    char* wsb = (char*)d_ws;
    size_t off = 0;
    auto alloc = [&](size_t bytes) -> void* {
        void* p = (void*)(wsb + off);
        off += bytes;
        off = (off + 255) & ~(size_t)255;
        return p;
    };

    int*    rs      = (int*)alloc(4 * (size_t)(N + 1));
    float*  invd    = (float*)alloc(4 * (size_t)N);
    float*  rinv    = (float*)alloc(4 * (size_t)N);
    int*    flag    = (int*)alloc(256);
    int*    bcount  = (int*)alloc(4 * 256);
    int*    bbase   = (int*)alloc(4 * 257);
    int*    bcursor = (int*)alloc(4 * 256);
    int*    csr     = (int*)alloc(4 * (size_t)E);
    ushort* ytab    = (ushort*)alloc((size_t)N * 128 * 2);  // [8][N][16] bf16
    ushort* yr      = (ushort*)alloc((size_t)N * 128 * 2);
    ushort* v       = (ushort*)alloc((size_t)N * 128 * 2);  // pre-norm rows
    ushort* Wp      = (ushort*)alloc(2 * 32768 * 2);
    uint*   pairbuf = (uint*)ytab;  // alias: dead before gemm writes ytab

    const int ab = (N + 3) / 4;
    const int mtiles = (N + 63) / 64;
    const int ntiles = (E + 2047) / 2048;

    // ---- CSR build (2-level binned, fused deg-scan) ----
    detect_kernel<<<1, 64, 0, stream>>>((const int*)ei, flag);
    hipMemsetAsync(bcount, 0, 4 * 256, stream);
    bucket_count_kernel<<<512, 256, 0, stream>>>(ei, flag, bcount, E);
    bucket_scan_kernel<<<1, 256, 0, stream>>>(bcount, bbase, bcursor, rs, N);
    bin_scatter_kernel<<<256, 256, 0, stream>>>(ei, flag, bcursor, pairbuf, E, ntiles);
    bucket_degscan_kernel<<<256, 256, 0, stream>>>(pairbuf, bbase, rs, invd, N);
    bucket_fill_kernel<<<256, 256, 0, stream>>>(pairbuf, bbase, rs, csr, N);

    // ---- weight packing ----
    pack_w_kernel<<<32, 256, 0, stream>>>(Wl1, Wr1, Wl2, Wr2, Wp);

    // ---- Layer 1: gemm (f32 A, inline cvt) -> slice gather -> rinv ----
    sage_mfma_gemm<1, 0><<<512, 256, 0, stream>>>(x, Wp, nullptr, ytab, yr, N, mtiles);
    slice_gather_kernel<<<1024, 256, 0, stream>>>(ytab, yr, bl1, csr, rs, invd, v, N);
    norm_kernel<0><<<ab, 256, 0, stream>>>(v, rinv, nullptr, N);

    // ---- Layer 2: gemm (bf16 A=v, fused normalize via rinv) -> gather -> out ----
    sage_mfma_gemm<0, 1><<<512, 256, 0, stream>>>(v, Wp + 32768, rinv, ytab, yr, N, mtiles);
    slice_gather_kernel<<<1024, 256, 0, stream>>>(ytab, yr, bl2, csr, rs, invd, v, N);
    norm_kernel<1><<<ab, 256, 0, stream>>>(v, nullptr, out, N);
}

// Round 6
// 275.557 us; speedup vs baseline: 4.0969x; 4.0969x over previous
//
#include <hip/hip_runtime.h>
#include <hip/hip_bf16.h>

// -------------------------------------------------------------------------
// SAGEConv encoder, 2 layers.
// Identity: mean_agg(x) @ Wl^T == mean_agg(x @ Wl^T)  (linearity).
// Per layer:
//   1) MFMA GEMM: yl = A@Wl^T (bf16), yr = A@Wr^T (bf16)
//   2) fused gather-mean(yl) + yr + bias + L2-normalize
//      (one node per 16-lane group: 4 nodes/wave, 16 row-loads in flight)
// CSR built once via 2-level binning with fused deg-scan.
// R5 lesson: do NOT channel-slice the gather table (8x gather count killed it).
// -------------------------------------------------------------------------

typedef __attribute__((ext_vector_type(8))) short bf16x8;
typedef __attribute__((ext_vector_type(4))) float f32x4;

__device__ __forceinline__ ushort f2bf(float f) {
    uint u = __float_as_uint(f);
    uint r = (u + 0x7FFFu + ((u >> 16) & 1u)) >> 16;   // RNE
    return (ushort)r;
}
__device__ __forceinline__ float bflo(uint u) { return __uint_as_float(u << 16); }
__device__ __forceinline__ float bfhi(uint u) { return __uint_as_float(u & 0xFFFF0000u); }

// ---- edge_index dtype detection (int32 vs int64) -------------------------
__global__ void detect_kernel(const int* __restrict__ ei, int* __restrict__ flag) {
    if (threadIdx.x == 0 && blockIdx.x == 0) {
        int z = 1;
        for (int j = 0; j < 64; ++j)
            if (ei[2 * j + 1] != 0) { z = 0; break; }
        *flag = z;  // 1 -> int64, 0 -> int32
    }
}

__device__ __forceinline__ int load_idx(const void* ei, int is64, size_t i) {
    return is64 ? (int)((const long long*)ei)[i] : ((const int*)ei)[i];
}

// ---- coarse bucket histogram (bucket = dst>>9, 256 buckets) --------------
__global__ __launch_bounds__(256) void bucket_count_kernel(
    const void* __restrict__ ei, const int* __restrict__ flagp,
    int* __restrict__ bcount, int E) {
    __shared__ int h[256];
    h[threadIdx.x] = 0;
    __syncthreads();
    const int is64 = *flagp;
    for (int i = blockIdx.x * 256 + threadIdx.x; i < E; i += gridDim.x * 256) {
        const int d = load_idx(ei, is64, (size_t)E + i);
        atomicAdd(&h[d >> 9], 1);
    }
    __syncthreads();
    atomicAdd(&bcount[threadIdx.x], h[threadIdx.x]);
}

// ---- 256-entry exclusive scan of bucket counts; also writes rs[N]=E ------
__global__ void bucket_scan_kernel(const int* __restrict__ bcount,
                                   int* __restrict__ bbase, int* __restrict__ bcursor,
                                   int* __restrict__ rs, int N) {
    __shared__ int wt[4];
    const int tid = threadIdx.x, lane = tid & 63, wid = tid >> 6;
    const int v = bcount[tid];
    int incl = v;
    for (int d = 1; d < 64; d <<= 1) {
        int up = __shfl_up(incl, d, 64);
        if (lane >= d) incl += up;
    }
    if (lane == 63) wt[wid] = incl;
    __syncthreads();
    int woff = 0;
    for (int w = 0; w < wid; ++w) woff += wt[w];
    const int excl = woff + incl - v;
    bbase[tid] = excl;
    bcursor[tid] = excl;
    if (tid == 255) {
        bbase[256] = woff + incl;   // == E
        rs[N] = woff + incl;
    }
}

// ---- scatter packed (dstlocal<<17)|src into bucket regions ---------------
__global__ __launch_bounds__(256) void bin_scatter_kernel(
    const void* __restrict__ ei, const int* __restrict__ flagp,
    int* __restrict__ bcursor, uint* __restrict__ pairbuf, int E, int ntiles) {
    __shared__ int cnt[256], pos[256];
    const int tid = threadIdx.x;
    const int is64 = *flagp;
    for (int tile = blockIdx.x; tile < ntiles; tile += gridDim.x) {
        const int base = tile * 2048;
        cnt[tid] = 0;
        __syncthreads();
        int eb[8];
        uint ep[8];
#pragma unroll
        for (int j = 0; j < 8; ++j) {
            const int i = base + tid * 8 + j;
            if (i < E) {
                const int s = load_idx(ei, is64, (size_t)i);
                const int d = load_idx(ei, is64, (size_t)E + i);
                eb[j] = d >> 9;
                ep[j] = ((uint)(d & 511) << 17) | (uint)s;
                atomicAdd(&cnt[eb[j]], 1);
            } else {
                eb[j] = -1;
            }
        }
        __syncthreads();
        pos[tid] = atomicAdd(&bcursor[tid], cnt[tid]);   // reserve range
        __syncthreads();
#pragma unroll
        for (int j = 0; j < 8; ++j) {
            if (eb[j] >= 0) {
                const int p = atomicAdd(&pos[eb[j]], 1);
                pairbuf[p] = ep[j];
            }
        }
    }
}

// ---- per-bucket degree count + fused exclusive scan -> rs, invd ----------
__global__ __launch_bounds__(256) void bucket_degscan_kernel(
    const uint* __restrict__ pairbuf, const int* __restrict__ bbase,
    int* __restrict__ rs, float* __restrict__ invd, int N) {
    __shared__ int dg[512];
    __shared__ int wt[4];
    const int tid = threadIdx.x, lane = tid & 63, wid = tid >> 6, wg = blockIdx.x;
    dg[tid] = 0;
    dg[tid + 256] = 0;
    __syncthreads();
    const int s = bbase[wg], e = bbase[wg + 1];
    for (int i = s + tid; i < e; i += 256)
        atomicAdd(&dg[pairbuf[i] >> 17], 1);
    __syncthreads();
    const int d0 = dg[2 * tid], d1 = dg[2 * tid + 1];
    const int v = d0 + d1;
    int incl = v;
    for (int d = 1; d < 64; d <<= 1) {
        int up = __shfl_up(incl, d, 64);
        if (lane >= d) incl += up;
    }
    if (lane == 63) wt[wid] = incl;
    __syncthreads();
    int woff = 0;
    for (int w = 0; w < wid; ++w) woff += wt[w];
    const int excl = woff + incl - v + bbase[wg];
    const int node = wg * 512 + 2 * tid;
    if (node < N) {
        rs[node] = excl;
        invd[node] = 1.0f / (float)(d0 > 1 ? d0 : 1);
    }
    if (node + 1 < N) {
        rs[node + 1] = excl + d0;
        invd[node + 1] = 1.0f / (float)(d1 > 1 ? d1 : 1);
    }
}

// ---- per-bucket CSR fill with LDS cursors --------------------------------
__global__ __launch_bounds__(256) void bucket_fill_kernel(
    const uint* __restrict__ pairbuf, const int* __restrict__ bbase,
    const int* __restrict__ rs, int* __restrict__ csr, int N) {
    __shared__ int cur[512];
    const int tid = threadIdx.x, wg = blockIdx.x;
#pragma unroll
    for (int t = tid; t < 512; t += 256) {
        const int node = wg * 512 + t;
        cur[t] = (node < N) ? rs[node] : 0;
    }
    __syncthreads();
    const int s = bbase[wg], e = bbase[wg + 1];
    for (int i = s + tid; i < e; i += 256) {
        const uint p = pairbuf[i];
        const int pos = atomicAdd(&cur[p >> 17], 1);
        csr[pos] = (int)(p & 0x1FFFFu);
    }
}

// ---- pack W into MFMA B-fragment layout ----------------------------------
__global__ void pack_w_kernel(const float* __restrict__ Wl1, const float* __restrict__ Wr1,
                              const float* __restrict__ Wl2, const float* __restrict__ Wr2,
                              ushort* __restrict__ Wp) {
    const int gtid = blockIdx.x * 256 + threadIdx.x;   // [0, 8192)
    if (gtid >= 8192) return;
    const int layer = gtid >> 12;
    const int c16   = gtid & 4095;
    const int s     = c16 >> 10;
    const int t     = (c16 >> 6) & 15;
    const int lane  = c16 & 63;
    const int c     = t * 16 + (lane & 15);
    const int kbase = s * 32 + (lane >> 4) * 8;
    const float* Wl = layer ? Wl2 : Wl1;
    const float* Wr = layer ? Wr2 : Wr1;
    const float* src = (c < 128) ? (Wl + c * 128 + kbase) : (Wr + (c - 128) * 128 + kbase);
    ushort* dst = Wp + (size_t)layer * 32768 + (size_t)c16 * 8;
#pragma unroll
    for (int j = 0; j < 8; ++j) dst[j] = f2bf(src[j]);
}

// ---- MFMA GEMM: A[n][128] @ W[256][128]^T -> yl[n][128], yr[n][128] ------
// A is f32 (AF32=1, inline bf16 convert) or bf16 (AF32=0).
template <int AF32>
__global__ __launch_bounds__(256) void sage_mfma_gemm(
    const void* __restrict__ Av, const ushort* __restrict__ Wp,
    ushort* __restrict__ yl, ushort* __restrict__ yr, int n, int mtiles) {
    __shared__ ushort Wlds[32768];
    for (int i = threadIdx.x; i < 4096; i += 256)
        *(bf16x8*)&Wlds[(size_t)i * 8] = *(const bf16x8*)&Wp[(size_t)i * 8];
    __syncthreads();

    const int wid = threadIdx.x >> 6, lane = threadIdx.x & 63;
    const int koff = (lane >> 4) * 8;
    const int rsub = lane & 15;

    int mt = blockIdx.x;
    if (mt >= mtiles) return;

    auto load_frags = [&](int arow, bf16x8* a) {
        if (AF32) {
            const float* ap = (const float*)Av + ((size_t)arow << 7) + koff;
#pragma unroll
            for (int s = 0; s < 4; ++s) {
                const float4 f0 = *(const float4*)(ap + s * 32);
                const float4 f1 = *(const float4*)(ap + s * 32 + 4);
                bf16x8 r;
                r[0] = (short)f2bf(f0.x); r[1] = (short)f2bf(f0.y);
                r[2] = (short)f2bf(f0.z); r[3] = (short)f2bf(f0.w);
                r[4] = (short)f2bf(f1.x); r[5] = (short)f2bf(f1.y);
                r[6] = (short)f2bf(f1.z); r[7] = (short)f2bf(f1.w);
                a[s] = r;
            }
        } else {
            const ushort* ap = (const ushort*)Av + ((size_t)arow << 7) + koff;
#pragma unroll
            for (int s = 0; s < 4; ++s) a[s] = *(const bf16x8*)(ap + s * 32);
        }
    };

    bf16x8 a_cur[4], a_nxt[4];
    {
        int arow = mt * 64 + wid * 16 + rsub;
        if (arow >= n) arow = 0;
        load_frags(arow, a_cur);
    }

    while (true) {
        const int mtn = mt + gridDim.x;
        if (mtn < mtiles) {
            int arow = mtn * 64 + wid * 16 + rsub;
            if (arow >= n) arow = 0;
            load_frags(arow, a_nxt);
        }

        f32x4 acc[16];
        const f32x4 zero = {0.f, 0.f, 0.f, 0.f};
#pragma unroll
        for (int t = 0; t < 16; ++t) acc[t] = zero;

#pragma unroll
        for (int s = 0; s < 4; ++s) {
            const bf16x8 as = a_cur[s];
#pragma unroll
            for (int t = 0; t < 16; ++t) {
                const bf16x8 b = *(const bf16x8*)&Wlds[(size_t)((s * 16 + t) * 64 + lane) * 8];
                acc[t] = __builtin_amdgcn_mfma_f32_16x16x32_bf16(as, b, acc[t], 0, 0, 0);
            }
        }

        // epilogue: C/D layout col=lane&15, row=(lane>>4)*4+reg
        const int rowb = mt * 64 + wid * 16 + (lane >> 4) * 4;
#pragma unroll
        for (int t = 0; t < 16; ++t) {
            ushort* dst = (t < 8) ? yl : yr;
            const int col = (t & 7) * 16 + rsub;
#pragma unroll
            for (int r = 0; r < 4; ++r) {
                const int row = rowb + r;
                if (row < n) dst[((size_t)row << 7) + col] = f2bf(acc[t][r]);
            }
        }

        if (mtn >= mtiles) break;
        mt = mtn;
#pragma unroll
        for (int s = 0; s < 4; ++s) a_cur[s] = a_nxt[s];
    }
}

// ---- fused gather-mean + yr + bias + L2-normalize ------------------------
// One node per 16-lane group (4 nodes/wave, independent streams).
// Lane t of a group holds channels 8t..8t+7; a group loads one 256B row per
// load; inner loop issues 4 row-loads back-to-back (csr via broadcast int4)
// -> 16 row-loads in flight per wave.
template <int OUTF32>
__global__ __launch_bounds__(256) void aggregate_norm_kernel(
    const ushort* __restrict__ yl, const ushort* __restrict__ yr,
    const float* __restrict__ bias, const int* __restrict__ csr,
    const int* __restrict__ rs, const float* __restrict__ invd,
    void* __restrict__ outp, int n) {
    const int wid = threadIdx.x >> 6, lane = threadIdx.x & 63;
    const int g = lane >> 4, t = lane & 15;
    const int node = blockIdx.x * 16 + wid * 4 + g;
    if (node >= n) return;
    const int s = rs[node], e = rs[node + 1];

    float ax[8];
#pragma unroll
    for (int j = 0; j < 8; ++j) ax[j] = 0.f;

    auto acc_row = [&](uint4 u) {
        ax[0] += bflo(u.x); ax[1] += bfhi(u.x);
        ax[2] += bflo(u.y); ax[3] += bfhi(u.y);
        ax[4] += bflo(u.z); ax[5] += bfhi(u.z);
        ax[6] += bflo(u.w); ax[7] += bfhi(u.w);
    };

    int q = s;
    // peel to 16B-aligned csr index
    while (q < e && (q & 3)) {
        const int c = csr[q++];
        acc_row(*(const uint4*)(yl + ((size_t)c << 7) + 8 * t));
    }
    for (; q + 4 <= e; q += 4) {
        const int4 c4 = *(const int4*)(csr + q);   // broadcast 16B load
        const uint4 u0 = *(const uint4*)(yl + ((size_t)c4.x << 7) + 8 * t);
        const uint4 u1 = *(const uint4*)(yl + ((size_t)c4.y << 7) + 8 * t);
        const uint4 u2 = *(const uint4*)(yl + ((size_t)c4.z << 7) + 8 * t);
        const uint4 u3 = *(const uint4*)(yl + ((size_t)c4.w << 7) + 8 * t);
        acc_row(u0); acc_row(u1); acc_row(u2); acc_row(u3);
    }
    for (; q < e; ++q) {
        const int c = csr[q];
        acc_row(*(const uint4*)(yl + ((size_t)c << 7) + 8 * t));
    }

    const float iv = invd[node];
    const uint4 ur = *(const uint4*)(yr + ((size_t)node << 7) + 8 * t);
    const float4 b0 = *(const float4*)(bias + 8 * t);
    const float4 b1 = *(const float4*)(bias + 8 * t + 4);
    float v[8];
    v[0] = fmaf(ax[0], iv, bflo(ur.x) + b0.x);
    v[1] = fmaf(ax[1], iv, bfhi(ur.x) + b0.y);
    v[2] = fmaf(ax[2], iv, bflo(ur.y) + b0.z);
    v[3] = fmaf(ax[3], iv, bfhi(ur.y) + b0.w);
    v[4] = fmaf(ax[4], iv, bflo(ur.z) + b1.x);
    v[5] = fmaf(ax[5], iv, bfhi(ur.z) + b1.y);
    v[6] = fmaf(ax[6], iv, bflo(ur.w) + b1.z);
    v[7] = fmaf(ax[7], iv, bfhi(ur.w) + b1.w);

    float ss = 0.f;
#pragma unroll
    for (int j = 0; j < 8; ++j) ss = fmaf(v[j], v[j], ss);
    // reduce within the 16-lane group
    ss += __shfl_xor(ss, 1, 64);
    ss += __shfl_xor(ss, 2, 64);
    ss += __shfl_xor(ss, 4, 64);
    ss += __shfl_xor(ss, 8, 64);
    const float sc = 1.0f / fmaxf(sqrtf(ss), 1e-12f);

    if (OUTF32) {
        float4 o0 = {v[0] * sc, v[1] * sc, v[2] * sc, v[3] * sc};
        float4 o1 = {v[4] * sc, v[5] * sc, v[6] * sc, v[7] * sc};
        ((float4*)outp)[((size_t)node << 5) + 2 * t]     = o0;
        ((float4*)outp)[((size_t)node << 5) + 2 * t + 1] = o1;
    } else {
        uint4 o;
        o.x = (uint)f2bf(v[0] * sc) | ((uint)f2bf(v[1] * sc) << 16);
        o.y = (uint)f2bf(v[2] * sc) | ((uint)f2bf(v[3] * sc) << 16);
        o.z = (uint)f2bf(v[4] * sc) | ((uint)f2bf(v[5] * sc) << 16);
        o.w = (uint)f2bf(v[6] * sc) | ((uint)f2bf(v[7] * sc) << 16);
        ((uint4*)outp)[((size_t)node << 4) + t] = o;
    }
}

// -------------------------------------------------------------------------
extern "C" void kernel_launch(void* const* d_in, const int* in_sizes, int n_in,
                              void* d_out, int out_size, void* d_ws, size_t ws_size,
                              hipStream_t stream) {
    const float* x   = (const float*)d_in[0];
    const void*  ei  = d_in[1];
    const float* Wl1 = (const float*)d_in[2];
    const float* bl1 = (const float*)d_in[3];
    const float* Wr1 = (const float*)d_in[4];
    const float* Wl2 = (const float*)d_in[5];
    const float* bl2 = (const float*)d_in[6];
    const float* Wr2 = (const float*)d_in[7];
    float* out = (float*)d_out;

    const int N = in_sizes[0] / 128;
    const int E = in_sizes[1] / 2;

    char* wsb = (char*)d_ws;
    size_t off = 0;
    auto alloc = [&](size_t bytes) -> void* {
        void* p = (void*)(wsb + off);
        off += bytes;
        off = (off + 255) & ~(size_t)255;
        return p;
    };

    int*    rs      = (int*)alloc(4 * (size_t)(N + 1));
    float*  invd    = (float*)alloc(4 * (size_t)N);
    int*    flag    = (int*)alloc(256);
    int*    bcount  = (int*)alloc(4 * 256);
    int*    bbase   = (int*)alloc(4 * 257);
    int*    bcursor = (int*)alloc(4 * 256);
    int*    csr     = (int*)alloc(4 * (size_t)E);
    ushort* h1      = (ushort*)alloc((size_t)N * 128 * 2);  // layer-1 output (bf16)
    ushort* yl      = (ushort*)alloc((size_t)N * 128 * 2);
    ushort* yr      = (ushort*)alloc((size_t)N * 128 * 2);
    ushort* Wp      = (ushort*)alloc(2 * 32768 * 2);
    uint*   pairbuf = (uint*)yl;   // alias: dead before gemm writes yl

    const int ab = (N + 15) / 16;
    const int mtiles = (N + 63) / 64;
    const int ntiles = (E + 2047) / 2048;

    // ---- CSR build (2-level binned, fused deg-scan) ----
    detect_kernel<<<1, 64, 0, stream>>>((const int*)ei, flag);
    hipMemsetAsync(bcount, 0, 4 * 256, stream);
    bucket_count_kernel<<<512, 256, 0, stream>>>(ei, flag, bcount, E);
    bucket_scan_kernel<<<1, 256, 0, stream>>>(bcount, bbase, bcursor, rs, N);
    bin_scatter_kernel<<<256, 256, 0, stream>>>(ei, flag, bcursor, pairbuf, E, ntiles);
    bucket_degscan_kernel<<<256, 256, 0, stream>>>(pairbuf, bbase, rs, invd, N);
    bucket_fill_kernel<<<256, 256, 0, stream>>>(pairbuf, bbase, rs, csr, N);

    // ---- weight packing ----
    pack_w_kernel<<<32, 256, 0, stream>>>(Wl1, Wr1, Wl2, Wr2, Wp);

    // ---- Layer 1: gemm (f32 A, inline cvt) -> fused gather+norm -> h1 ----
    sage_mfma_gemm<1><<<512, 256, 0, stream>>>(x, Wp, yl, yr, N, mtiles);
    aggregate_norm_kernel<0><<<ab, 256, 0, stream>>>(yl, yr, bl1, csr, rs, invd, h1, N);

    // ---- Layer 2: gemm (bf16 A=h1) -> fused gather+norm -> f32 out ----
    sage_mfma_gemm<0><<<512, 256, 0, stream>>>(h1, Wp + 32768, yl, yr, N, mtiles);
    aggregate_norm_kernel<1><<<ab, 256, 0, stream>>>(yl, yr, bl2, csr, rs, invd, out, N);
}

// Round 8
// 272.413 us; speedup vs baseline: 4.1442x; 1.0115x over previous
//
#include <hip/hip_runtime.h>
#include <hip/hip_bf16.h>

// -------------------------------------------------------------------------
// SAGEConv encoder, 2 layers.
// Identity: mean_agg(x) @ Wl^T == mean_agg(x @ Wl^T)  (linearity).
// Per layer:
//   1) MFMA GEMM: yl = A@Wl^T (bf16), yr = A@Wr^T (bf16)
//   2) fused gather-mean(yl) + yr + bias + L2-normalize
//      (one node per 16-lane group; 8 row-loads back-to-back per group)
// CSR build: SINGLE pass over edge_index -> fixed-capacity bucket regions
// (256 buckets of 512 nodes, cap 16384), then per-bucket deg-scan + fill.
// R5 lesson: do NOT channel-slice the gather table (8x gather count).
// R6 lesson: gather is fabric-bound at ~3.7TB/s / 193MB compulsory misses.
// R7 lesson: __builtin_nontemporal_* needs clang ext_vector types, not
//            HIP_vector_type wrappers (int4/uint4/float4).
// -------------------------------------------------------------------------

#define BCAP 16384   // per-bucket region capacity (E/256 avg = 6250)

typedef __attribute__((ext_vector_type(8))) short bf16x8;
typedef __attribute__((ext_vector_type(4))) float f32x4;
typedef __attribute__((ext_vector_type(4))) int   intv4;
typedef __attribute__((ext_vector_type(4))) uint  uintv4;

__device__ __forceinline__ ushort f2bf(float f) {
    uint u = __float_as_uint(f);
    uint r = (u + 0x7FFFu + ((u >> 16) & 1u)) >> 16;   // RNE
    return (ushort)r;
}
__device__ __forceinline__ float bflo(uint u) { return __uint_as_float(u << 16); }
__device__ __forceinline__ float bfhi(uint u) { return __uint_as_float(u & 0xFFFF0000u); }

// ---- edge_index dtype detection (int32 vs int64) -------------------------
__global__ void detect_kernel(const int* __restrict__ ei, int* __restrict__ flag) {
    if (threadIdx.x == 0 && blockIdx.x == 0) {
        int z = 1;
        for (int j = 0; j < 64; ++j)
            if (ei[2 * j + 1] != 0) { z = 0; break; }
        *flag = z;  // 1 -> int64, 0 -> int32
    }
}

__device__ __forceinline__ int load_idx(const void* ei, int is64, size_t i) {
    return is64 ? (int)((const long long*)ei)[i] : ((const int*)ei)[i];
}

// ---- single-pass scatter into fixed bucket regions -----------------------
// pairbuf[b*BCAP + off] = (dstlocal<<17) | src, bucket b = dst>>9.
__global__ __launch_bounds__(256) void bin_scatter_kernel(
    const void* __restrict__ ei, const int* __restrict__ flagp,
    int* __restrict__ bcursor, uint* __restrict__ pairbuf, int E, int ntiles) {
    __shared__ int cnt[256], pos[256];
    const int tid = threadIdx.x;
    const int is64 = *flagp;
    for (int tile = blockIdx.x; tile < ntiles; tile += gridDim.x) {
        const int base = tile * 2048;
        cnt[tid] = 0;
        __syncthreads();
        int eb[8];
        uint ep[8];
#pragma unroll
        for (int j = 0; j < 8; ++j) {
            const int i = base + tid * 8 + j;
            if (i < E) {
                const int s = load_idx(ei, is64, (size_t)i);
                const int d = load_idx(ei, is64, (size_t)E + i);
                eb[j] = d >> 9;
                ep[j] = ((uint)(d & 511) << 17) | (uint)s;
                atomicAdd(&cnt[eb[j]], 1);
            } else {
                eb[j] = -1;
            }
        }
        __syncthreads();
        pos[tid] = atomicAdd(&bcursor[tid], cnt[tid]);   // bucket-relative start
        __syncthreads();
#pragma unroll
        for (int j = 0; j < 8; ++j) {
            if (eb[j] >= 0) {
                const int p = atomicAdd(&pos[eb[j]], 1);
                if (p < BCAP) pairbuf[(size_t)eb[j] * BCAP + p] = ep[j];
            }
        }
    }
}

// ---- 256-entry exclusive scan of bucket counts -> csr base offsets -------
__global__ void bucket_scan_kernel(const int* __restrict__ bcount,
                                   int* __restrict__ bbase,
                                   int* __restrict__ rs, int N) {
    __shared__ int wt[4];
    const int tid = threadIdx.x, lane = tid & 63, wid = tid >> 6;
    const int v = bcount[tid];
    int incl = v;
    for (int d = 1; d < 64; d <<= 1) {
        int up = __shfl_up(incl, d, 64);
        if (lane >= d) incl += up;
    }
    if (lane == 63) wt[wid] = incl;
    __syncthreads();
    int woff = 0;
    for (int w = 0; w < wid; ++w) woff += wt[w];
    bbase[tid] = woff + incl - v;
    if (tid == 255) rs[N] = woff + incl;   // == E
}

// ---- per-bucket degree count + fused exclusive scan -> rs, invd ----------
__global__ __launch_bounds__(256) void bucket_degscan_kernel(
    const uint* __restrict__ pairbuf, const int* __restrict__ bcount,
    const int* __restrict__ bbase,
    int* __restrict__ rs, float* __restrict__ invd, int N) {
    __shared__ int dg[512];
    __shared__ int wt[4];
    const int tid = threadIdx.x, lane = tid & 63, wid = tid >> 6, wg = blockIdx.x;
    dg[tid] = 0;
    dg[tid + 256] = 0;
    __syncthreads();
    const int s = wg * BCAP, e = s + bcount[wg];
    for (int i = s + tid; i < e; i += 256)
        atomicAdd(&dg[pairbuf[i] >> 17], 1);
    __syncthreads();
    const int d0 = dg[2 * tid], d1 = dg[2 * tid + 1];
    const int v = d0 + d1;
    int incl = v;
    for (int d = 1; d < 64; d <<= 1) {
        int up = __shfl_up(incl, d, 64);
        if (lane >= d) incl += up;
    }
    if (lane == 63) wt[wid] = incl;
    __syncthreads();
    int woff = 0;
    for (int w = 0; w < wid; ++w) woff += wt[w];
    const int excl = woff + incl - v + bbase[wg];
    const int node = wg * 512 + 2 * tid;
    if (node < N) {
        rs[node] = excl;
        invd[node] = 1.0f / (float)(d0 > 1 ? d0 : 1);
    }
    if (node + 1 < N) {
        rs[node + 1] = excl + d0;
        invd[node + 1] = 1.0f / (float)(d1 > 1 ? d1 : 1);
    }
}

// ---- per-bucket CSR fill with LDS cursors --------------------------------
__global__ __launch_bounds__(256) void bucket_fill_kernel(
    const uint* __restrict__ pairbuf, const int* __restrict__ bcount,
    const int* __restrict__ rs, int* __restrict__ csr, int N) {
    __shared__ int cur[512];
    const int tid = threadIdx.x, wg = blockIdx.x;
#pragma unroll
    for (int t = tid; t < 512; t += 256) {
        const int node = wg * 512 + t;
        cur[t] = (node < N) ? rs[node] : 0;
    }
    __syncthreads();
    const int s = wg * BCAP, e = s + bcount[wg];
    for (int i = s + tid; i < e; i += 256) {
        const uint p = pairbuf[i];
        const int pos = atomicAdd(&cur[p >> 17], 1);
        csr[pos] = (int)(p & 0x1FFFFu);
    }
}

// ---- pack W into MFMA B-fragment layout ----------------------------------
__global__ void pack_w_kernel(const float* __restrict__ Wl1, const float* __restrict__ Wr1,
                              const float* __restrict__ Wl2, const float* __restrict__ Wr2,
                              ushort* __restrict__ Wp) {
    const int gtid = blockIdx.x * 256 + threadIdx.x;   // [0, 8192)
    if (gtid >= 8192) return;
    const int layer = gtid >> 12;
    const int c16   = gtid & 4095;
    const int s     = c16 >> 10;
    const int t     = (c16 >> 6) & 15;
    const int lane  = c16 & 63;
    const int c     = t * 16 + (lane & 15);
    const int kbase = s * 32 + (lane >> 4) * 8;
    const float* Wl = layer ? Wl2 : Wl1;
    const float* Wr = layer ? Wr2 : Wr1;
    const float* src = (c < 128) ? (Wl + c * 128 + kbase) : (Wr + (c - 128) * 128 + kbase);
    ushort* dst = Wp + (size_t)layer * 32768 + (size_t)c16 * 8;
#pragma unroll
    for (int j = 0; j < 8; ++j) dst[j] = f2bf(src[j]);
}

// ---- MFMA GEMM: A[n][128] @ W[256][128]^T -> yl[n][128], yr[n][128] ------
// A is f32 (AF32=1, inline bf16 convert) or bf16 (AF32=0).
template <int AF32>
__global__ __launch_bounds__(256) void sage_mfma_gemm(
    const void* __restrict__ Av, const ushort* __restrict__ Wp,
    ushort* __restrict__ yl, ushort* __restrict__ yr, int n, int mtiles) {
    __shared__ ushort Wlds[32768];
    for (int i = threadIdx.x; i < 4096; i += 256)
        *(bf16x8*)&Wlds[(size_t)i * 8] = *(const bf16x8*)&Wp[(size_t)i * 8];
    __syncthreads();

    const int wid = threadIdx.x >> 6, lane = threadIdx.x & 63;
    const int koff = (lane >> 4) * 8;
    const int rsub = lane & 15;

    int mt = blockIdx.x;
    if (mt >= mtiles) return;

    auto load_frags = [&](int arow, bf16x8* a) {
        if (AF32) {
            const float* ap = (const float*)Av + ((size_t)arow << 7) + koff;
#pragma unroll
            for (int s = 0; s < 4; ++s) {
                const float4 f0 = *(const float4*)(ap + s * 32);
                const float4 f1 = *(const float4*)(ap + s * 32 + 4);
                bf16x8 r;
                r[0] = (short)f2bf(f0.x); r[1] = (short)f2bf(f0.y);
                r[2] = (short)f2bf(f0.z); r[3] = (short)f2bf(f0.w);
                r[4] = (short)f2bf(f1.x); r[5] = (short)f2bf(f1.y);
                r[6] = (short)f2bf(f1.z); r[7] = (short)f2bf(f1.w);
                a[s] = r;
            }
        } else {
            const ushort* ap = (const ushort*)Av + ((size_t)arow << 7) + koff;
#pragma unroll
            for (int s = 0; s < 4; ++s) a[s] = *(const bf16x8*)(ap + s * 32);
        }
    };

    bf16x8 a_cur[4], a_nxt[4];
    {
        int arow = mt * 64 + wid * 16 + rsub;
        if (arow >= n) arow = 0;
        load_frags(arow, a_cur);
    }

    while (true) {
        const int mtn = mt + gridDim.x;
        if (mtn < mtiles) {
            int arow = mtn * 64 + wid * 16 + rsub;
            if (arow >= n) arow = 0;
            load_frags(arow, a_nxt);
        }

        f32x4 acc[16];
        const f32x4 zero = {0.f, 0.f, 0.f, 0.f};
#pragma unroll
        for (int t = 0; t < 16; ++t) acc[t] = zero;

#pragma unroll
        for (int s = 0; s < 4; ++s) {
            const bf16x8 as = a_cur[s];
#pragma unroll
            for (int t = 0; t < 16; ++t) {
                const bf16x8 b = *(const bf16x8*)&Wlds[(size_t)((s * 16 + t) * 64 + lane) * 8];
                acc[t] = __builtin_amdgcn_mfma_f32_16x16x32_bf16(as, b, acc[t], 0, 0, 0);
            }
        }

        // epilogue: C/D layout col=lane&15, row=(lane>>4)*4+reg
        const int rowb = mt * 64 + wid * 16 + (lane >> 4) * 4;
#pragma unroll
        for (int t = 0; t < 16; ++t) {
            ushort* dst = (t < 8) ? yl : yr;
            const int col = (t & 7) * 16 + rsub;
#pragma unroll
            for (int r = 0; r < 4; ++r) {
                const int row = rowb + r;
                if (row < n) dst[((size_t)row << 7) + col] = f2bf(acc[t][r]);
            }
        }

        if (mtn >= mtiles) break;
        mt = mtn;
#pragma unroll
        for (int s = 0; s < 4; ++s) a_cur[s] = a_nxt[s];
    }
}

// ---- fused gather-mean + yr + bias + L2-normalize ------------------------
// One node per 16-lane group (4 nodes/wave). Lane t holds channels 8t..8t+7.
// Inner loop issues 8 row-loads back-to-back (csr via broadcast intv4 pairs)
// -> 32 row-loads in flight per wave. csr/rs/yr streams use nontemporal
// loads to keep the yl table resident in L2.
template <int OUTF32>
__global__ __launch_bounds__(256) void aggregate_norm_kernel(
    const ushort* __restrict__ yl, const ushort* __restrict__ yr,
    const float* __restrict__ bias, const int* __restrict__ csr,
    const int* __restrict__ rs, const float* __restrict__ invd,
    void* __restrict__ outp, int n) {
    const int wid = threadIdx.x >> 6, lane = threadIdx.x & 63;
    const int g = lane >> 4, t = lane & 15;
    const int node = blockIdx.x * 16 + wid * 4 + g;
    if (node >= n) return;
    const int s = __builtin_nontemporal_load(&rs[node]);
    const int e = __builtin_nontemporal_load(&rs[node + 1]);

    float ax[8];
#pragma unroll
    for (int j = 0; j < 8; ++j) ax[j] = 0.f;

    auto acc_row = [&](uintv4 u) {
        ax[0] += bflo(u.x); ax[1] += bfhi(u.x);
        ax[2] += bflo(u.y); ax[3] += bfhi(u.y);
        ax[4] += bflo(u.z); ax[5] += bfhi(u.z);
        ax[6] += bflo(u.w); ax[7] += bfhi(u.w);
    };

    int q = s;
    // peel to 16B-aligned csr index
    while (q < e && (q & 3)) {
        const int c = csr[q++];
        acc_row(*(const uintv4*)(yl + ((size_t)c << 7) + 8 * t));
    }
    for (; q + 8 <= e; q += 8) {
        const intv4 c0 = __builtin_nontemporal_load((const intv4*)(csr + q));
        const intv4 c1 = __builtin_nontemporal_load((const intv4*)(csr + q + 4));
        const uintv4 u0 = *(const uintv4*)(yl + ((size_t)c0.x << 7) + 8 * t);
        const uintv4 u1 = *(const uintv4*)(yl + ((size_t)c0.y << 7) + 8 * t);
        const uintv4 u2 = *(const uintv4*)(yl + ((size_t)c0.z << 7) + 8 * t);
        const uintv4 u3 = *(const uintv4*)(yl + ((size_t)c0.w << 7) + 8 * t);
        const uintv4 u4 = *(const uintv4*)(yl + ((size_t)c1.x << 7) + 8 * t);
        const uintv4 u5 = *(const uintv4*)(yl + ((size_t)c1.y << 7) + 8 * t);
        const uintv4 u6 = *(const uintv4*)(yl + ((size_t)c1.z << 7) + 8 * t);
        const uintv4 u7 = *(const uintv4*)(yl + ((size_t)c1.w << 7) + 8 * t);
        acc_row(u0); acc_row(u1); acc_row(u2); acc_row(u3);
        acc_row(u4); acc_row(u5); acc_row(u6); acc_row(u7);
    }
    if (q + 4 <= e) {
        const intv4 c4 = __builtin_nontemporal_load((const intv4*)(csr + q));
        const uintv4 u0 = *(const uintv4*)(yl + ((size_t)c4.x << 7) + 8 * t);
        const uintv4 u1 = *(const uintv4*)(yl + ((size_t)c4.y << 7) + 8 * t);
        const uintv4 u2 = *(const uintv4*)(yl + ((size_t)c4.z << 7) + 8 * t);
        const uintv4 u3 = *(const uintv4*)(yl + ((size_t)c4.w << 7) + 8 * t);
        acc_row(u0); acc_row(u1); acc_row(u2); acc_row(u3);
        q += 4;
    }
    for (; q < e; ++q) {
        const int c = csr[q];
        acc_row(*(const uintv4*)(yl + ((size_t)c << 7) + 8 * t));
    }

    const float iv = invd[node];
    const uintv4 ur = __builtin_nontemporal_load((const uintv4*)(yr + ((size_t)node << 7) + 8 * t));
    const float4 b0 = *(const float4*)(bias + 8 * t);
    const float4 b1 = *(const float4*)(bias + 8 * t + 4);
    float v[8];
    v[0] = fmaf(ax[0], iv, bflo(ur.x) + b0.x);
    v[1] = fmaf(ax[1], iv, bfhi(ur.x) + b0.y);
    v[2] = fmaf(ax[2], iv, bflo(ur.y) + b0.z);
    v[3] = fmaf(ax[3], iv, bfhi(ur.y) + b0.w);
    v[4] = fmaf(ax[4], iv, bflo(ur.z) + b1.x);
    v[5] = fmaf(ax[5], iv, bfhi(ur.z) + b1.y);
    v[6] = fmaf(ax[6], iv, bflo(ur.w) + b1.z);
    v[7] = fmaf(ax[7], iv, bfhi(ur.w) + b1.w);

    float ss = 0.f;
#pragma unroll
    for (int j = 0; j < 8; ++j) ss = fmaf(v[j], v[j], ss);
    // reduce within the 16-lane group
    ss += __shfl_xor(ss, 1, 64);
    ss += __shfl_xor(ss, 2, 64);
    ss += __shfl_xor(ss, 4, 64);
    ss += __shfl_xor(ss, 8, 64);
    const float sc = 1.0f / fmaxf(sqrtf(ss), 1e-12f);

    if (OUTF32) {
        f32x4 o0 = {v[0] * sc, v[1] * sc, v[2] * sc, v[3] * sc};
        f32x4 o1 = {v[4] * sc, v[5] * sc, v[6] * sc, v[7] * sc};
        __builtin_nontemporal_store(o0, (f32x4*)outp + ((size_t)node << 5) + 2 * t);
        __builtin_nontemporal_store(o1, (f32x4*)outp + ((size_t)node << 5) + 2 * t + 1);
    } else {
        uintv4 o;
        o.x = (uint)f2bf(v[0] * sc) | ((uint)f2bf(v[1] * sc) << 16);
        o.y = (uint)f2bf(v[2] * sc) | ((uint)f2bf(v[3] * sc) << 16);
        o.z = (uint)f2bf(v[4] * sc) | ((uint)f2bf(v[5] * sc) << 16);
        o.w = (uint)f2bf(v[6] * sc) | ((uint)f2bf(v[7] * sc) << 16);
        __builtin_nontemporal_store(o, (uintv4*)outp + ((size_t)node << 4) + t);
    }
}

// -------------------------------------------------------------------------
extern "C" void kernel_launch(void* const* d_in, const int* in_sizes, int n_in,
                              void* d_out, int out_size, void* d_ws, size_t ws_size,
                              hipStream_t stream) {
    const float* x   = (const float*)d_in[0];
    const void*  ei  = d_in[1];
    const float* Wl1 = (const float*)d_in[2];
    const float* bl1 = (const float*)d_in[3];
    const float* Wr1 = (const float*)d_in[4];
    const float* Wl2 = (const float*)d_in[5];
    const float* bl2 = (const float*)d_in[6];
    const float* Wr2 = (const float*)d_in[7];
    float* out = (float*)d_out;

    const int N = in_sizes[0] / 128;
    const int E = in_sizes[1] / 2;

    char* wsb = (char*)d_ws;
    size_t off = 0;
    auto alloc = [&](size_t bytes) -> void* {
        void* p = (void*)(wsb + off);
        off += bytes;
        off = (off + 255) & ~(size_t)255;
        return p;
    };

    int*    rs      = (int*)alloc(4 * (size_t)(N + 1));
    float*  invd    = (float*)alloc(4 * (size_t)N);
    int*    flag    = (int*)alloc(256);
    int*    bcursor = (int*)alloc(4 * 256);   // bucket counts after scatter
    int*    bbase   = (int*)alloc(4 * 256);   // csr base offset per bucket
    int*    csr     = (int*)alloc(4 * (size_t)E);
    ushort* h1      = (ushort*)alloc((size_t)N * 128 * 2);  // layer-1 output (bf16)
    ushort* yl      = (ushort*)alloc((size_t)N * 128 * 2);
    ushort* yr      = (ushort*)alloc((size_t)N * 128 * 2);
    ushort* Wp      = (ushort*)alloc(2 * 32768 * 2);
    uint*   pairbuf = (uint*)yl;   // 256*BCAP*4B = 16.8MB <= yl (25.6MB); dead before gemm

    const int ab = (N + 15) / 16;
    const int mtiles = (N + 63) / 64;
    const int ntiles = (E + 2047) / 2048;

    // ---- CSR build: single ei pass into fixed bucket regions ----
    detect_kernel<<<1, 64, 0, stream>>>((const int*)ei, flag);
    hipMemsetAsync(bcursor, 0, 4 * 256, stream);
    bin_scatter_kernel<<<512, 256, 0, stream>>>(ei, flag, bcursor, pairbuf, E, ntiles);
    bucket_scan_kernel<<<1, 256, 0, stream>>>(bcursor, bbase, rs, N);
    bucket_degscan_kernel<<<256, 256, 0, stream>>>(pairbuf, bcursor, bbase, rs, invd, N);
    bucket_fill_kernel<<<256, 256, 0, stream>>>(pairbuf, bcursor, rs, csr, N);

    // ---- weight packing ----
    pack_w_kernel<<<32, 256, 0, stream>>>(Wl1, Wr1, Wl2, Wr2, Wp);

    // ---- Layer 1: gemm (f32 A, inline cvt) -> fused gather+norm -> h1 ----
    sage_mfma_gemm<1><<<512, 256, 0, stream>>>(x, Wp, yl, yr, N, mtiles);
    aggregate_norm_kernel<0><<<ab, 256, 0, stream>>>(yl, yr, bl1, csr, rs, invd, h1, N);

    // ---- Layer 2: gemm (bf16 A=h1) -> fused gather+norm -> f32 out ----
    sage_mfma_gemm<0><<<512, 256, 0, stream>>>(h1, Wp + 32768, yl, yr, N, mtiles);
    aggregate_norm_kernel<1><<<ab, 256, 0, stream>>>(yl, yr, bl2, csr, rs, invd, out, N);
}

// Round 9
// 229.627 us; speedup vs baseline: 4.9164x; 1.1863x over previous
//
#include <hip/hip_runtime.h>
#include <hip/hip_bf16.h>

// -------------------------------------------------------------------------
// SAGEConv encoder, 2 layers.
// Identity: mean_agg(x) @ Wl^T == mean_agg(x @ Wl^T)  (linearity).
// Per layer:
//   1) MFMA GEMM: ylq = rowwise-int8(A@Wl^T) + scales, yr = A@Wr^T (bf16)
//   2) fused gather-mean(ylq,scales) + yr + bias + L2-normalize
//      (one node per 16-lane group; R6 structure, 4 rows in flight)
// CSR build: SINGLE pass over edge_index -> fixed-capacity bucket regions.
// R5 lesson: do NOT channel-slice the gather table (8x gather count).
// R6 lesson: gather is traffic-bound: per-XCD compulsory table re-fetch.
// R8 lesson: deep unroll + NT loads cost occupancy with no BW gain.
// This round: halve table bytes via per-row-scaled u8 (worst-case decode
// error ~m/254 -> <=0.0015 on normalized output even at degree 1).
// -------------------------------------------------------------------------

#define BCAP 16384   // per-bucket region capacity (E/256 avg = 6250)

typedef __attribute__((ext_vector_type(8))) short bf16x8;
typedef __attribute__((ext_vector_type(4))) float f32x4;

__device__ __forceinline__ ushort f2bf(float f) {
    uint u = __float_as_uint(f);
    uint r = (u + 0x7FFFu + ((u >> 16) & 1u)) >> 16;   // RNE
    return (ushort)r;
}
__device__ __forceinline__ float bflo(uint u) { return __uint_as_float(u << 16); }
__device__ __forceinline__ float bfhi(uint u) { return __uint_as_float(u & 0xFFFF0000u); }

// ---- edge_index dtype detection (int32 vs int64) -------------------------
__global__ void detect_kernel(const int* __restrict__ ei, int* __restrict__ flag) {
    if (threadIdx.x == 0 && blockIdx.x == 0) {
        int z = 1;
        for (int j = 0; j < 64; ++j)
            if (ei[2 * j + 1] != 0) { z = 0; break; }
        *flag = z;  // 1 -> int64, 0 -> int32
    }
}

__device__ __forceinline__ int load_idx(const void* ei, int is64, size_t i) {
    return is64 ? (int)((const long long*)ei)[i] : ((const int*)ei)[i];
}

// ---- single-pass scatter into fixed bucket regions -----------------------
// pairbuf[b*BCAP + off] = (dstlocal<<17) | src, bucket b = dst>>9.
__global__ __launch_bounds__(256) void bin_scatter_kernel(
    const void* __restrict__ ei, const int* __restrict__ flagp,
    int* __restrict__ bcursor, uint* __restrict__ pairbuf, int E, int ntiles) {
    __shared__ int cnt[256], pos[256];
    const int tid = threadIdx.x;
    const int is64 = *flagp;
    for (int tile = blockIdx.x; tile < ntiles; tile += gridDim.x) {
        const int base = tile * 2048;
        cnt[tid] = 0;
        __syncthreads();
        int eb[8];
        uint ep[8];
#pragma unroll
        for (int j = 0; j < 8; ++j) {
            const int i = base + tid * 8 + j;
            if (i < E) {
                const int s = load_idx(ei, is64, (size_t)i);
                const int d = load_idx(ei, is64, (size_t)E + i);
                eb[j] = d >> 9;
                ep[j] = ((uint)(d & 511) << 17) | (uint)s;
                atomicAdd(&cnt[eb[j]], 1);
            } else {
                eb[j] = -1;
            }
        }
        __syncthreads();
        pos[tid] = atomicAdd(&bcursor[tid], cnt[tid]);   // bucket-relative start
        __syncthreads();
#pragma unroll
        for (int j = 0; j < 8; ++j) {
            if (eb[j] >= 0) {
                const int p = atomicAdd(&pos[eb[j]], 1);
                if (p < BCAP) pairbuf[(size_t)eb[j] * BCAP + p] = ep[j];
            }
        }
    }
}

// ---- 256-entry exclusive scan of bucket counts -> csr base offsets -------
__global__ void bucket_scan_kernel(const int* __restrict__ bcount,
                                   int* __restrict__ bbase,
                                   int* __restrict__ rs, int N) {
    __shared__ int wt[4];
    const int tid = threadIdx.x, lane = tid & 63, wid = tid >> 6;
    const int v = bcount[tid];
    int incl = v;
    for (int d = 1; d < 64; d <<= 1) {
        int up = __shfl_up(incl, d, 64);
        if (lane >= d) incl += up;
    }
    if (lane == 63) wt[wid] = incl;
    __syncthreads();
    int woff = 0;
    for (int w = 0; w < wid; ++w) woff += wt[w];
    bbase[tid] = woff + incl - v;
    if (tid == 255) rs[N] = woff + incl;   // == E
}

// ---- per-bucket degree count + fused exclusive scan -> rs, invd ----------
__global__ __launch_bounds__(256) void bucket_degscan_kernel(
    const uint* __restrict__ pairbuf, const int* __restrict__ bcount,
    const int* __restrict__ bbase,
    int* __restrict__ rs, float* __restrict__ invd, int N) {
    __shared__ int dg[512];
    __shared__ int wt[4];
    const int tid = threadIdx.x, lane = tid & 63, wid = tid >> 6, wg = blockIdx.x;
    dg[tid] = 0;
    dg[tid + 256] = 0;
    __syncthreads();
    const int s = wg * BCAP, e = s + bcount[wg];
    for (int i = s + tid; i < e; i += 256)
        atomicAdd(&dg[pairbuf[i] >> 17], 1);
    __syncthreads();
    const int d0 = dg[2 * tid], d1 = dg[2 * tid + 1];
    const int v = d0 + d1;
    int incl = v;
    for (int d = 1; d < 64; d <<= 1) {
        int up = __shfl_up(incl, d, 64);
        if (lane >= d) incl += up;
    }
    if (lane == 63) wt[wid] = incl;
    __syncthreads();
    int woff = 0;
    for (int w = 0; w < wid; ++w) woff += wt[w];
    const int excl = woff + incl - v + bbase[wg];
    const int node = wg * 512 + 2 * tid;
    if (node < N) {
        rs[node] = excl;
        invd[node] = 1.0f / (float)(d0 > 1 ? d0 : 1);
    }
    if (node + 1 < N) {
        rs[node + 1] = excl + d0;
        invd[node + 1] = 1.0f / (float)(d1 > 1 ? d1 : 1);
    }
}

// ---- per-bucket CSR fill with LDS cursors --------------------------------
__global__ __launch_bounds__(256) void bucket_fill_kernel(
    const uint* __restrict__ pairbuf, const int* __restrict__ bcount,
    const int* __restrict__ rs, int* __restrict__ csr, int N) {
    __shared__ int cur[512];
    const int tid = threadIdx.x, wg = blockIdx.x;
#pragma unroll
    for (int t = tid; t < 512; t += 256) {
        const int node = wg * 512 + t;
        cur[t] = (node < N) ? rs[node] : 0;
    }
    __syncthreads();
    const int s = wg * BCAP, e = s + bcount[wg];
    for (int i = s + tid; i < e; i += 256) {
        const uint p = pairbuf[i];
        const int pos = atomicAdd(&cur[p >> 17], 1);
        csr[pos] = (int)(p & 0x1FFFFu);
    }
}

// ---- pack W into MFMA B-fragment layout ----------------------------------
__global__ void pack_w_kernel(const float* __restrict__ Wl1, const float* __restrict__ Wr1,
                              const float* __restrict__ Wl2, const float* __restrict__ Wr2,
                              ushort* __restrict__ Wp) {
    const int gtid = blockIdx.x * 256 + threadIdx.x;   // [0, 8192)
    if (gtid >= 8192) return;
    const int layer = gtid >> 12;
    const int c16   = gtid & 4095;
    const int s     = c16 >> 10;
    const int t     = (c16 >> 6) & 15;
    const int lane  = c16 & 63;
    const int c     = t * 16 + (lane & 15);
    const int kbase = s * 32 + (lane >> 4) * 8;
    const float* Wl = layer ? Wl2 : Wl1;
    const float* Wr = layer ? Wr2 : Wr1;
    const float* src = (c < 128) ? (Wl + c * 128 + kbase) : (Wr + (c - 128) * 128 + kbase);
    ushort* dst = Wp + (size_t)layer * 32768 + (size_t)c16 * 8;
#pragma unroll
    for (int j = 0; j < 8; ++j) dst[j] = f2bf(src[j]);
}

// ---- MFMA GEMM: A[n][128] @ W[256][128]^T --------------------------------
// cols 0..127  -> per-row-scaled u8 table ylq[n][128] + scales[n]
// cols 128..255-> yr[n][128] bf16
// A is f32 (AF32=1, inline bf16 convert) or bf16 (AF32=0).
template <int AF32>
__global__ __launch_bounds__(256) void sage_mfma_gemm(
    const void* __restrict__ Av, const ushort* __restrict__ Wp,
    unsigned char* __restrict__ ylq, float* __restrict__ scales,
    ushort* __restrict__ yr, int n, int mtiles) {
    __shared__ ushort Wlds[32768];
    for (int i = threadIdx.x; i < 4096; i += 256)
        *(bf16x8*)&Wlds[(size_t)i * 8] = *(const bf16x8*)&Wp[(size_t)i * 8];
    __syncthreads();

    const int wid = threadIdx.x >> 6, lane = threadIdx.x & 63;
    const int koff = (lane >> 4) * 8;
    const int rsub = lane & 15;

    int mt = blockIdx.x;
    if (mt >= mtiles) return;

    auto load_frags = [&](int arow, bf16x8* a) {
        if (AF32) {
            const float* ap = (const float*)Av + ((size_t)arow << 7) + koff;
#pragma unroll
            for (int s = 0; s < 4; ++s) {
                const float4 f0 = *(const float4*)(ap + s * 32);
                const float4 f1 = *(const float4*)(ap + s * 32 + 4);
                bf16x8 r;
                r[0] = (short)f2bf(f0.x); r[1] = (short)f2bf(f0.y);
                r[2] = (short)f2bf(f0.z); r[3] = (short)f2bf(f0.w);
                r[4] = (short)f2bf(f1.x); r[5] = (short)f2bf(f1.y);
                r[6] = (short)f2bf(f1.z); r[7] = (short)f2bf(f1.w);
                a[s] = r;
            }
        } else {
            const ushort* ap = (const ushort*)Av + ((size_t)arow << 7) + koff;
#pragma unroll
            for (int s = 0; s < 4; ++s) a[s] = *(const bf16x8*)(ap + s * 32);
        }
    };

    bf16x8 a_cur[4], a_nxt[4];
    {
        int arow = mt * 64 + wid * 16 + rsub;
        if (arow >= n) arow = 0;
        load_frags(arow, a_cur);
    }

    while (true) {
        const int mtn = mt + gridDim.x;
        if (mtn < mtiles) {
            int arow = mtn * 64 + wid * 16 + rsub;
            if (arow >= n) arow = 0;
            load_frags(arow, a_nxt);
        }

        f32x4 acc[16];
        const f32x4 zero = {0.f, 0.f, 0.f, 0.f};
#pragma unroll
        for (int t = 0; t < 16; ++t) acc[t] = zero;

#pragma unroll
        for (int s = 0; s < 4; ++s) {
            const bf16x8 as = a_cur[s];
#pragma unroll
            for (int t = 0; t < 16; ++t) {
                const bf16x8 b = *(const bf16x8*)&Wlds[(size_t)((s * 16 + t) * 64 + lane) * 8];
                acc[t] = __builtin_amdgcn_mfma_f32_16x16x32_bf16(as, b, acc[t], 0, 0, 0);
            }
        }

        // epilogue: C/D layout col=lane&15, row=(lane>>4)*4+reg
        const int rowb = mt * 64 + wid * 16 + (lane >> 4) * 4;

        // --- yl part: per-row u8 quantization ---
        float mrow[4], invq[4];
#pragma unroll
        for (int r = 0; r < 4; ++r) {
            float m = 0.f;
#pragma unroll
            for (int t = 0; t < 8; ++t) m = fmaxf(m, fabsf(acc[t][r]));
            m = fmaxf(m, __shfl_xor(m, 1, 64));
            m = fmaxf(m, __shfl_xor(m, 2, 64));
            m = fmaxf(m, __shfl_xor(m, 4, 64));
            m = fmaxf(m, __shfl_xor(m, 8, 64));
            mrow[r] = m;
            invq[r] = 127.0f / fmaxf(m, 1e-20f);
        }
        if (rsub == 0) {
#pragma unroll
            for (int r = 0; r < 4; ++r)
                if (rowb + r < n) scales[rowb + r] = mrow[r] * (1.0f / 127.0f);
        }
#pragma unroll
        for (int t = 0; t < 8; ++t) {
            const int col = t * 16 + rsub;
#pragma unroll
            for (int r = 0; r < 4; ++r) {
                const int row = rowb + r;
                if (row < n) {
                    const int qv = __float2int_rn(acc[t][r] * invq[r]) + 128;
                    ylq[((size_t)row << 7) + col] = (unsigned char)qv;
                }
            }
        }
        // --- yr part: bf16 ---
#pragma unroll
        for (int t = 8; t < 16; ++t) {
            const int col = (t - 8) * 16 + rsub;
#pragma unroll
            for (int r = 0; r < 4; ++r) {
                const int row = rowb + r;
                if (row < n) yr[((size_t)row << 7) + col] = f2bf(acc[t][r]);
            }
        }

        if (mtn >= mtiles) break;
        mt = mtn;
#pragma unroll
        for (int s = 0; s < 4; ++s) a_cur[s] = a_nxt[s];
    }
}

// ---- fused gather-mean (u8 table) + yr + bias + L2-normalize -------------
// One node per 16-lane group (4 nodes/wave). Lane t holds channels 8t..8t+7.
// Inner loop: 4 rows in flight (csr via broadcast int4), u8 rows decoded as
// (b - 128)*scale accumulated via ax += b*s with sumS correction.
template <int OUTF32>
__global__ __launch_bounds__(256) void aggregate_norm_kernel(
    const unsigned char* __restrict__ ylq, const float* __restrict__ scales,
    const ushort* __restrict__ yr, const float* __restrict__ bias,
    const int* __restrict__ csr, const int* __restrict__ rs,
    const float* __restrict__ invd, void* __restrict__ outp, int n) {
    const int wid = threadIdx.x >> 6, lane = threadIdx.x & 63;
    const int g = lane >> 4, t = lane & 15;
    const int node = blockIdx.x * 16 + wid * 4 + g;
    if (node >= n) return;
    const int s = rs[node], e = rs[node + 1];

    float ax[8];
#pragma unroll
    for (int j = 0; j < 8; ++j) ax[j] = 0.f;
    float sumS = 0.f;

    auto acc_row = [&](uint2 u, float sc) {
        sumS += sc;
        ax[0] = fmaf((float)(u.x & 0xffu),         sc, ax[0]);
        ax[1] = fmaf((float)((u.x >> 8) & 0xffu),  sc, ax[1]);
        ax[2] = fmaf((float)((u.x >> 16) & 0xffu), sc, ax[2]);
        ax[3] = fmaf((float)(u.x >> 24),           sc, ax[3]);
        ax[4] = fmaf((float)(u.y & 0xffu),         sc, ax[4]);
        ax[5] = fmaf((float)((u.y >> 8) & 0xffu),  sc, ax[5]);
        ax[6] = fmaf((float)((u.y >> 16) & 0xffu), sc, ax[6]);
        ax[7] = fmaf((float)(u.y >> 24),           sc, ax[7]);
    };

    int q = s;
    // peel to 16B-aligned csr index
    while (q < e && (q & 3)) {
        const int c = csr[q++];
        acc_row(*(const uint2*)(ylq + ((size_t)c << 7) + 8 * t), scales[c]);
    }
    for (; q + 4 <= e; q += 4) {
        const int4 c4 = *(const int4*)(csr + q);   // broadcast 16B load
        const float s0 = scales[c4.x], s1 = scales[c4.y];
        const float s2 = scales[c4.z], s3 = scales[c4.w];
        const uint2 u0 = *(const uint2*)(ylq + ((size_t)c4.x << 7) + 8 * t);
        const uint2 u1 = *(const uint2*)(ylq + ((size_t)c4.y << 7) + 8 * t);
        const uint2 u2 = *(const uint2*)(ylq + ((size_t)c4.z << 7) + 8 * t);
        const uint2 u3 = *(const uint2*)(ylq + ((size_t)c4.w << 7) + 8 * t);
        acc_row(u0, s0); acc_row(u1, s1); acc_row(u2, s2); acc_row(u3, s3);
    }
    for (; q < e; ++q) {
        const int c = csr[q];
        acc_row(*(const uint2*)(ylq + ((size_t)c << 7) + 8 * t), scales[c]);
    }

    const float iv = invd[node];
    const float base = -128.0f * sumS;
    const uint4 ur = *(const uint4*)(yr + ((size_t)node << 7) + 8 * t);
    const float4 b0 = *(const float4*)(bias + 8 * t);
    const float4 b1 = *(const float4*)(bias + 8 * t + 4);
    float v[8];
    v[0] = fmaf(ax[0] + base, iv, bflo(ur.x) + b0.x);
    v[1] = fmaf(ax[1] + base, iv, bfhi(ur.x) + b0.y);
    v[2] = fmaf(ax[2] + base, iv, bflo(ur.y) + b0.z);
    v[3] = fmaf(ax[3] + base, iv, bfhi(ur.y) + b0.w);
    v[4] = fmaf(ax[4] + base, iv, bflo(ur.z) + b1.x);
    v[5] = fmaf(ax[5] + base, iv, bfhi(ur.z) + b1.y);
    v[6] = fmaf(ax[6] + base, iv, bflo(ur.w) + b1.z);
    v[7] = fmaf(ax[7] + base, iv, bfhi(ur.w) + b1.w);

    float ss = 0.f;
#pragma unroll
    for (int j = 0; j < 8; ++j) ss = fmaf(v[j], v[j], ss);
    // reduce within the 16-lane group
    ss += __shfl_xor(ss, 1, 64);
    ss += __shfl_xor(ss, 2, 64);
    ss += __shfl_xor(ss, 4, 64);
    ss += __shfl_xor(ss, 8, 64);
    const float sc = 1.0f / fmaxf(sqrtf(ss), 1e-12f);

    if (OUTF32) {
        float4 o0 = {v[0] * sc, v[1] * sc, v[2] * sc, v[3] * sc};
        float4 o1 = {v[4] * sc, v[5] * sc, v[6] * sc, v[7] * sc};
        ((float4*)outp)[((size_t)node << 5) + 2 * t]     = o0;
        ((float4*)outp)[((size_t)node << 5) + 2 * t + 1] = o1;
    } else {
        uint4 o;
        o.x = (uint)f2bf(v[0] * sc) | ((uint)f2bf(v[1] * sc) << 16);
        o.y = (uint)f2bf(v[2] * sc) | ((uint)f2bf(v[3] * sc) << 16);
        o.z = (uint)f2bf(v[4] * sc) | ((uint)f2bf(v[5] * sc) << 16);
        o.w = (uint)f2bf(v[6] * sc) | ((uint)f2bf(v[7] * sc) << 16);
        ((uint4*)outp)[((size_t)node << 4) + t] = o;
    }
}

// -------------------------------------------------------------------------
extern "C" void kernel_launch(void* const* d_in, const int* in_sizes, int n_in,
                              void* d_out, int out_size, void* d_ws, size_t ws_size,
                              hipStream_t stream) {
    const float* x   = (const float*)d_in[0];
    const void*  ei  = d_in[1];
    const float* Wl1 = (const float*)d_in[2];
    const float* bl1 = (const float*)d_in[3];
    const float* Wr1 = (const float*)d_in[4];
    const float* Wl2 = (const float*)d_in[5];
    const float* bl2 = (const float*)d_in[6];
    const float* Wr2 = (const float*)d_in[7];
    float* out = (float*)d_out;

    const int N = in_sizes[0] / 128;
    const int E = in_sizes[1] / 2;

    char* wsb = (char*)d_ws;
    size_t off = 0;
    auto alloc = [&](size_t bytes) -> void* {
        void* p = (void*)(wsb + off);
        off += bytes;
        off = (off + 255) & ~(size_t)255;
        return p;
    };

    int*    rs      = (int*)alloc(4 * (size_t)(N + 1));
    float*  invd    = (float*)alloc(4 * (size_t)N);
    float*  scales  = (float*)alloc(4 * (size_t)N);
    int*    flag    = (int*)alloc(256);
    int*    bcursor = (int*)alloc(4 * 256);   // bucket counts after scatter
    int*    bbase   = (int*)alloc(4 * 256);   // csr base offset per bucket
    int*    csr     = (int*)alloc(4 * (size_t)E);
    ushort* h1      = (ushort*)alloc((size_t)N * 128 * 2);  // layer-1 output (bf16)
    unsigned char* ylq = (unsigned char*)alloc((size_t)N * 128);
    ushort* yr      = (ushort*)alloc((size_t)N * 128 * 2);
    ushort* Wp      = (ushort*)alloc(2 * 32768 * 2);
    uint*   pairbuf = (uint*)yr;   // 256*BCAP*4B = 16.8MB <= yr (25.6MB); dead before gemm

    const int ab = (N + 15) / 16;
    const int mtiles = (N + 63) / 64;
    const int ntiles = (E + 2047) / 2048;

    // ---- CSR build: single ei pass into fixed bucket regions ----
    detect_kernel<<<1, 64, 0, stream>>>((const int*)ei, flag);
    hipMemsetAsync(bcursor, 0, 4 * 256, stream);
    bin_scatter_kernel<<<512, 256, 0, stream>>>(ei, flag, bcursor, pairbuf, E, ntiles);
    bucket_scan_kernel<<<1, 256, 0, stream>>>(bcursor, bbase, rs, N);
    bucket_degscan_kernel<<<256, 256, 0, stream>>>(pairbuf, bcursor, bbase, rs, invd, N);
    bucket_fill_kernel<<<256, 256, 0, stream>>>(pairbuf, bcursor, rs, csr, N);

    // ---- weight packing ----
    pack_w_kernel<<<32, 256, 0, stream>>>(Wl1, Wr1, Wl2, Wr2, Wp);

    // ---- Layer 1: gemm (f32 A, inline cvt) -> fused gather+norm -> h1 ----
    sage_mfma_gemm<1><<<512, 256, 0, stream>>>(x, Wp, ylq, scales, yr, N, mtiles);
    aggregate_norm_kernel<0><<<ab, 256, 0, stream>>>(ylq, scales, yr, bl1, csr, rs, invd, h1, N);

    // ---- Layer 2: gemm (bf16 A=h1) -> fused gather+norm -> f32 out ----
    sage_mfma_gemm<0><<<512, 256, 0, stream>>>(h1, Wp + 32768, ylq, scales, yr, N, mtiles);
    aggregate_norm_kernel<1><<<ab, 256, 0, stream>>>(ylq, scales, yr, bl2, csr, rs, invd, out, N);
}